// Round 2
// baseline (1208.674 us; speedup 1.0000x reference)
//
#include <hip/hip_runtime.h>

#define B_     10000
#define T_     80
#define E_     100
#define VOCAB_ 10000
#define U_     64
#define HP     72        // padded h row stride (72%32=8 -> rows land on distinct banks)

__device__ __forceinline__ float tanh_fast(float v) {
    float e  = __expf(2.0f * fabsf(v));      // overflow -> inf -> tanh -> 1
    float tn = 1.0f - 2.0f / (e + 1.0f);
    return copysignf(tn, v);
}

// ---------------- kernel 1: PROJ[v][u] = b[u] + sum_e emb[v][e] * Wx[e][u] ----------------
__global__ __launch_bounds__(256, 4)
void proj_emb(const float* __restrict__ emb, const float* __restrict__ Wx,
              const float* __restrict__ bias, float* __restrict__ proj)
{
    __shared__ __align__(16) float Wxs[E_ * U_];   // 25.6 KB
    __shared__ float bs[U_];
    const int tid = threadIdx.x;
    for (int i = tid; i < E_ * U_; i += 256) Wxs[i] = Wx[i];
    if (tid < U_) bs[tid] = bias[tid];
    __syncthreads();

    const int u    = tid & 63;
    const int vloc = tid >> 6;                     // 0..3 (wave id; uniform per wave)
    for (int v0 = blockIdx.x * 4; v0 < VOCAB_; v0 += gridDim.x * 4) {
        const int v = v0 + vloc;                   // v0 multiple of 4, <=9996 -> v<=9999
        const float* erow = emb + v * E_;          // 400 B rows -> 16B aligned
        float acc = bs[u];
        #pragma unroll
        for (int e = 0; e < E_; e += 4) {
            float4 ev = *reinterpret_cast<const float4*>(erow + e);
            acc += ev.x * Wxs[(e + 0) * U_ + u];
            acc += ev.y * Wxs[(e + 1) * U_ + u];
            acc += ev.z * Wxs[(e + 2) * U_ + u];
            acc += ev.w * Wxs[(e + 3) * U_ + u];
        }
        proj[v * U_ + u] = acc;
    }
}

// ---------------- kernel 2: recurrence, 4 rows/wave, no per-step barriers ----------------
// block = 128 threads = 2 waves = 8 batch rows. 1250 blocks (exact).
// lane layout: row = wave*4 + (lane>>4); 16 lanes/row, each owns 4 units (u0 = (lane&15)*4).
__global__ __launch_bounds__(128, 4)
void rnn_rec(const int* __restrict__ tokens, const float* __restrict__ Wh,
             const float* __restrict__ proj, const float* __restrict__ Wfc,
             const float* __restrict__ bfc, float* __restrict__ out)
{
    __shared__ __align__(16) float Whs[U_ * U_];   // 16 KB, shared by both waves
    __shared__ __align__(16) float hs[8 * HP];     // wave-private row slices
    __shared__ int toks[8 * T_];                   // 2.5 KB

    const int tid  = threadIdx.x;
    const int w    = tid >> 6;
    const int l    = tid & 63;
    const int wr   = (w << 2) + (l >> 4);          // block-row 0..7
    const int sub  = l & 15;
    const int u0   = sub << 2;
    const int grow = blockIdx.x * 8 + wr;

    for (int i = tid; i < U_ * U_; i += 128) Whs[i] = Wh[i];
    for (int i = tid; i < 8 * T_; i += 128) {
        int rr = i / T_, tt = i - rr * T_;
        toks[i] = tokens[(blockIdx.x * 8 + rr) * T_ + tt];
    }
    // wave-local h init (own rows only)
    for (int i = l; i < 4 * HP; i += 64) hs[(w << 2) * HP + i] = 0.0f;
    __syncthreads();                               // the ONLY barrier

    const int*   tokrow = toks + wr * T_;
    float*       hrow   = hs + wr * HP;            // 288 B stride -> 16B aligned
    const float4* proj4 = reinterpret_cast<const float4*>(proj);

    float4 x = proj4[tokrow[0] * 16 + sub];        // xp(t=0), bias folded in
    float4 hn;

    for (int t = 0; t < T_; ++t) {
        // prefetch next step's projection (hidden under this step's compute)
        const int tn = tokrow[(t + 1 < T_) ? (t + 1) : (T_ - 1)];
        float4 xn = proj4[tn * 16 + sub];

        float a0 = x.x, a1 = x.y, a2 = x.z, a3 = x.w;
        #pragma unroll
        for (int k = 0; k < U_; k += 4) {
            float4 hv = *reinterpret_cast<const float4*>(hrow + k);   // broadcast within row
            const float* hk = reinterpret_cast<const float*>(&hv);
            #pragma unroll
            for (int kk = 0; kk < 4; ++kk) {
                float4 wv = *reinterpret_cast<const float4*>(Whs + (k + kk) * U_ + u0);
                float hh = hk[kk];
                a0 += hh * wv.x; a1 += hh * wv.y;
                a2 += hh * wv.z; a3 += hh * wv.w;
            }
        }

        hn.x = tanh_fast(a0); hn.y = tanh_fast(a1);
        hn.z = tanh_fast(a2); hn.w = tanh_fast(a3);

        // all h(t-1) reads above precede this write in wave program order;
        // lgkmcnt ordering (same LDS array) makes it visible before next iter's reads
        *reinterpret_cast<float4*>(hrow + u0) = hn;
        x = xn;
    }

    // logits + sigmoid: dot(h, Wfc) reduced across the 16 lanes of this row
    float part = hn.x * Wfc[u0] + hn.y * Wfc[u0 + 1] + hn.z * Wfc[u0 + 2] + hn.w * Wfc[u0 + 3];
    part += __shfl_xor(part, 1);
    part += __shfl_xor(part, 2);
    part += __shfl_xor(part, 4);
    part += __shfl_xor(part, 8);
    if (sub == 0) {
        float logit = part + bfc[0];
        float s;
        if (logit >= 0.0f) s = 1.0f / (1.0f + __expf(-logit));
        else { float e = __expf(logit); s = e / (1.0f + e); }
        out[grow] = s;
    }
}

extern "C" void kernel_launch(void* const* d_in, const int* in_sizes, int n_in,
                              void* d_out, int out_size, void* d_ws, size_t ws_size,
                              hipStream_t stream) {
    const int*   tokens = (const int*)  d_in[0];
    const float* emb    = (const float*)d_in[1];
    const float* Wx     = (const float*)d_in[2];
    const float* Wh     = (const float*)d_in[3];
    const float* b      = (const float*)d_in[4];
    const float* Wfc    = (const float*)d_in[5];
    const float* bfc    = (const float*)d_in[6];
    float* out          = (float*)d_out;

    float* proj = (float*)d_ws;                    // VOCAB_*U_*4 = 2.56 MB scratch

    proj_emb<<<512, 256, 0, stream>>>(emb, Wx, b, proj);
    rnn_rec<<<B_ / 8, 128, 0, stream>>>(tokens, Wh, proj, Wfc, bfc, out);
}

// Round 3
// 334.097 us; speedup vs baseline: 3.6177x; 3.6177x over previous
//
#include <hip/hip_runtime.h>
#include <stdint.h>

#define B_     10000
#define T_     80
#define E_     100
#define VOCAB_ 10000
#define U_     64

typedef __attribute__((ext_vector_type(8))) short bf16x8;
typedef __attribute__((ext_vector_type(4))) float f32x4;

union FragU { bf16x8 v; uint32_t u[4]; short s[8]; };

__device__ __forceinline__ void split_bf16(float w, short& hi, short& lo) {
    uint32_t wb  = __float_as_uint(w);
    uint32_t hib = wb & 0xFFFF0000u;
    float rem = w - __uint_as_float(hib);
    hi = (short)(hib >> 16);
    lo = (short)(__float_as_uint(rem) >> 16);
}

__device__ __forceinline__ float tanh_fast(float v) {
    float e  = __expf(2.0f * fabsf(v));      // overflow -> inf -> tanh -> 1
    float tn = 1.0f - 2.0f / (e + 1.0f);
    return copysignf(tn, v);
}

__device__ __forceinline__ float sigmoid_f(float logit) {
    if (logit >= 0.0f) return 1.0f / (1.0f + __expf(-logit));
    float e = __expf(logit);
    return e / (1.0f + e);
}

// ============ kernel 1: xp[t][b][u] = emb[tok[b][t]] @ Wx + bias  (bf16 MFMA, 3-term hi/lo) ============
// one wave per block; wave owns 16 consecutive flat rows m = t*B_ + b (B_%16==0 -> same t).
__global__ __launch_bounds__(64, 1)
void expand_mfma(const int* __restrict__ tokens, const float* __restrict__ emb,
                 const float* __restrict__ Wx, const float* __restrict__ bias,
                 float* __restrict__ xp)
{
    const int l = threadIdx.x;
    const int q = l >> 4, p = l & 15;
    const int m0 = blockIdx.x * 16;
    const int t  = m0 / B_;
    const int b0 = m0 - t * B_;

    // ---- B-fragments of Wx (K padded 100->128), hi/lo ----
    FragU bxh[4][4], bxl[4][4];
    #pragma unroll
    for (int kk = 0; kk < 4; ++kk)
        #pragma unroll
        for (int n = 0; n < 4; ++n)
            #pragma unroll
            for (int j = 0; j < 8; ++j) {
                int k = 8 * q + j + 32 * kk;
                float w = (k < E_) ? Wx[k * U_ + 16 * n + p] : 0.0f;
                split_bf16(w, bxh[kk][n].s[j], bxl[kk][n].s[j]);
            }

    // ---- A-fragments: lane provides emb[tok[row p]][8q+32kk .. +7] ----
    const int tokp = tokens[(b0 + p) * T_ + t];
    const float* arow = emb + (size_t)tokp * E_;

    FragU axh[4], axl[4];
    #pragma unroll
    for (int kk = 0; kk < 4; ++kk) {
        const int k0 = 8 * q + 32 * kk;
        float av[8];
        if (k0 + 7 < E_) {
            f32x4 v0 = *(const f32x4*)(arow + k0);
            f32x4 v1 = *(const f32x4*)(arow + k0 + 4);
            av[0]=v0[0]; av[1]=v0[1]; av[2]=v0[2]; av[3]=v0[3];
            av[4]=v1[0]; av[5]=v1[1]; av[6]=v1[2]; av[7]=v1[3];
        } else if (k0 < E_) {                       // k0 == 96: exactly 4 valid
            f32x4 v0 = *(const f32x4*)(arow + k0);
            av[0]=v0[0]; av[1]=v0[1]; av[2]=v0[2]; av[3]=v0[3];
            av[4]=0; av[5]=0; av[6]=0; av[7]=0;
        } else {
            #pragma unroll
            for (int j = 0; j < 8; ++j) av[j] = 0.0f;
        }
        #pragma unroll
        for (int j = 0; j < 8; ++j) split_bf16(av[j], axh[kk].s[j], axl[kk].s[j]);
    }

    // ---- C = bias, accumulate 3-term ----
    f32x4 acc[4];
    #pragma unroll
    for (int n = 0; n < 4; ++n) {
        float bv = bias[16 * n + p];
        f32x4 a = {bv, bv, bv, bv};
        acc[n] = a;
    }
    #pragma unroll
    for (int kk = 0; kk < 4; ++kk)
        #pragma unroll
        for (int n = 0; n < 4; ++n) {
            acc[n] = __builtin_amdgcn_mfma_f32_16x16x32_bf16(axh[kk].v, bxh[kk][n].v, acc[n], 0, 0, 0);
            acc[n] = __builtin_amdgcn_mfma_f32_16x16x32_bf16(axl[kk].v, bxh[kk][n].v, acc[n], 0, 0, 0);
            acc[n] = __builtin_amdgcn_mfma_f32_16x16x32_bf16(axh[kk].v, bxl[kk][n].v, acc[n], 0, 0, 0);
        }

    // ---- write (sequential across the wave) ----
    #pragma unroll
    for (int n = 0; n < 4; ++n)
        #pragma unroll
        for (int r = 0; r < 4; ++r)
            xp[(size_t)(m0 + 4 * q + r) * U_ + 16 * n + p] = acc[n][r];
}

// ============ kernel 1b (fallback): proj[v][u] = emb[v]@Wx + b ============
__global__ __launch_bounds__(256, 4)
void proj_emb(const float* __restrict__ emb, const float* __restrict__ Wx,
              const float* __restrict__ bias, float* __restrict__ proj)
{
    __shared__ __align__(16) float Wxs[E_ * U_];
    __shared__ float bs[U_];
    const int tid = threadIdx.x;
    for (int i = tid; i < E_ * U_; i += 256) Wxs[i] = Wx[i];
    if (tid < U_) bs[tid] = bias[tid];
    __syncthreads();
    const int u = tid & 63, vloc = tid >> 6;
    for (int v0 = blockIdx.x * 4; v0 < VOCAB_; v0 += gridDim.x * 4) {
        const int v = v0 + vloc;
        const float* erow = emb + v * E_;
        float acc = bs[u];
        #pragma unroll
        for (int e = 0; e < E_; e += 4) {
            f32x4 ev = *(const f32x4*)(erow + e);
            acc += ev[0] * Wxs[(e + 0) * U_ + u];
            acc += ev[1] * Wxs[(e + 1) * U_ + u];
            acc += ev[2] * Wxs[(e + 2) * U_ + u];
            acc += ev[3] * Wxs[(e + 3) * U_ + u];
        }
        proj[v * U_ + u] = acc;
    }
}

// ============ kernel 2: recurrence. 1 wave = 16 rows, 80 steps, zero barriers ============
template<int GATHER>
__global__ __launch_bounds__(64, 1)
void rnn_mfma(const int* __restrict__ tokens, const float* __restrict__ Wh,
              const float* __restrict__ xsrc,   // GATHER ? proj[v][64] : xp[t][b][64]
              const float* __restrict__ Wfc, const float* __restrict__ bfc,
              float* __restrict__ out)
{
    __shared__ __align__(16) uint32_t H2[16 * 64];   // packed (hi<<16|lo) bf16 of h, XOR-swizzled
    const int l = threadIdx.x;
    const int q = l >> 4, p = l & 15;
    const int R0 = blockIdx.x * 16;
    const int swz = (p & 7) << 2;

    // ---- Wh fragments in registers (loop-invariant), hi/lo ----
    FragU bh[2][4], bl[2][4];
    #pragma unroll
    for (int kk = 0; kk < 2; ++kk)
        #pragma unroll
        for (int n = 0; n < 4; ++n)
            #pragma unroll
            for (int j = 0; j < 8; ++j) {
                float w = Wh[(8 * q + j + 32 * kk) * U_ + 16 * n + p];
                split_bf16(w, bh[kk][n].s[j], bl[kk][n].s[j]);
            }

    // ---- h(0) = 0 ----
    #pragma unroll
    for (int n = 0; n < 4; ++n)
        #pragma unroll
        for (int r = 0; r < 4; ++r) {
            int row = 4 * q + r;
            H2[row * 64 + ((16 * n + p) ^ ((row & 7) << 2))] = 0u;
        }

    float xn[16], hl[16];

    // ---- x loader ----
    #define LOADX(tt, xv)                                                          \
        if (GATHER) {                                                              \
            _Pragma("unroll")                                                      \
            for (int r = 0; r < 4; ++r) {                                          \
                int tok = tokens[(R0 + 4 * q + r) * T_ + (tt)];                    \
                const float* src = xsrc + (size_t)tok * U_ + p;                    \
                _Pragma("unroll")                                                  \
                for (int n = 0; n < 4; ++n) xv[r * 4 + n] = src[16 * n];           \
            }                                                                      \
        } else {                                                                   \
            const float* src = xsrc + ((size_t)(tt) * B_ + R0 + 4 * q) * U_ + p;   \
            _Pragma("unroll")                                                      \
            for (int r = 0; r < 4; ++r)                                            \
                _Pragma("unroll")                                                  \
                for (int n = 0; n < 4; ++n) xv[r * 4 + n] = src[r * 64 + 16 * n];  \
        }

    LOADX(0, xn)

    const uint32_t* Hrow = H2 + p * 64;

    for (int t = 0; t < T_; ++t) {
        // C-init = xp(t)
        f32x4 acc[4];
        #pragma unroll
        for (int n = 0; n < 4; ++n) {
            f32x4 a = {xn[0 * 4 + n], xn[1 * 4 + n], xn[2 * 4 + n], xn[3 * 4 + n]};
            acc[n] = a;
        }
        // prefetch xp(t+1)
        float xf[16];
        const int tnext = (t + 1 < T_) ? t + 1 : t;
        LOADX(tnext, xf)

        // A-fragments of h(t-1) from LDS (transpose read + unpack hi/lo via v_perm)
        FragU ah[2], al[2];
        #pragma unroll
        for (int kk = 0; kk < 2; ++kk) {
            const int c0 = 8 * q + 32 * kk;
            uint4 wa = *(const uint4*)(Hrow + (c0 ^ swz));
            uint4 wb = *(const uint4*)(Hrow + ((c0 + 4) ^ swz));
            ah[kk].u[0] = __builtin_amdgcn_perm(wa.y, wa.x, 0x07060302u);
            ah[kk].u[1] = __builtin_amdgcn_perm(wa.w, wa.z, 0x07060302u);
            ah[kk].u[2] = __builtin_amdgcn_perm(wb.y, wb.x, 0x07060302u);
            ah[kk].u[3] = __builtin_amdgcn_perm(wb.w, wb.z, 0x07060302u);
            al[kk].u[0] = __builtin_amdgcn_perm(wa.y, wa.x, 0x05040100u);
            al[kk].u[1] = __builtin_amdgcn_perm(wa.w, wa.z, 0x05040100u);
            al[kk].u[2] = __builtin_amdgcn_perm(wb.y, wb.x, 0x05040100u);
            al[kk].u[3] = __builtin_amdgcn_perm(wb.w, wb.z, 0x05040100u);
        }

        // h @ Wh : 3-term hi/lo, 24 MFMA
        #pragma unroll
        for (int kk = 0; kk < 2; ++kk)
            #pragma unroll
            for (int n = 0; n < 4; ++n) {
                acc[n] = __builtin_amdgcn_mfma_f32_16x16x32_bf16(ah[kk].v, bh[kk][n].v, acc[n], 0, 0, 0);
                acc[n] = __builtin_amdgcn_mfma_f32_16x16x32_bf16(al[kk].v, bh[kk][n].v, acc[n], 0, 0, 0);
                acc[n] = __builtin_amdgcn_mfma_f32_16x16x32_bf16(ah[kk].v, bl[kk][n].v, acc[n], 0, 0, 0);
            }

        // tanh, keep f32 copy, pack hi|lo back to LDS
        #pragma unroll
        for (int n = 0; n < 4; ++n)
            #pragma unroll
            for (int r = 0; r < 4; ++r) {
                float h = tanh_fast(acc[n][r]);
                hl[r * 4 + n] = h;
                uint32_t hb  = __float_as_uint(h);
                uint32_t hib = hb & 0xFFFF0000u;
                float rem = h - __uint_as_float(hib);
                uint32_t packed = hib | (__float_as_uint(rem) >> 16);
                int row = 4 * q + r;
                H2[row * 64 + ((16 * n + p) ^ ((row & 7) << 2))] = packed;
            }

        #pragma unroll
        for (int i = 0; i < 16; ++i) xn[i] = xf[i];
    }

    // ---- logits + sigmoid ----
    float wf[4];
    #pragma unroll
    for (int n = 0; n < 4; ++n) wf[n] = Wfc[16 * n + p];
    #pragma unroll
    for (int r = 0; r < 4; ++r) {
        float part = hl[r * 4 + 0] * wf[0] + hl[r * 4 + 1] * wf[1]
                   + hl[r * 4 + 2] * wf[2] + hl[r * 4 + 3] * wf[3];
        part += __shfl_xor(part, 1);
        part += __shfl_xor(part, 2);
        part += __shfl_xor(part, 4);
        part += __shfl_xor(part, 8);
        if (p == 0) out[R0 + 4 * q + r] = sigmoid_f(part + bfc[0]);
    }
}

extern "C" void kernel_launch(void* const* d_in, const int* in_sizes, int n_in,
                              void* d_out, int out_size, void* d_ws, size_t ws_size,
                              hipStream_t stream) {
    const int*   tokens = (const int*)  d_in[0];
    const float* emb    = (const float*)d_in[1];
    const float* Wx     = (const float*)d_in[2];
    const float* Wh     = (const float*)d_in[3];
    const float* b      = (const float*)d_in[4];
    const float* Wfc    = (const float*)d_in[5];
    const float* bfc    = (const float*)d_in[6];
    float* out          = (float*)d_out;

    const size_t needXP = (size_t)T_ * B_ * U_ * sizeof(float);   // 204.8 MB

    if (ws_size >= needXP) {
        float* xp = (float*)d_ws;
        expand_mfma<<<(T_ * B_) / 16, 64, 0, stream>>>(tokens, emb, Wx, b, xp);
        rnn_mfma<0><<<B_ / 16, 64, 0, stream>>>(tokens, Wh, xp, Wfc, bfc, out);
    } else {
        float* proj = (float*)d_ws;                               // 2.56 MB
        proj_emb<<<512, 256, 0, stream>>>(emb, Wx, b, proj);
        rnn_mfma<1><<<B_ / 16, 64, 0, stream>>>(tokens, Wh, proj, Wfc, bfc, out);
    }
}

// Round 4
// 184.653 us; speedup vs baseline: 6.5457x; 1.8093x over previous
//
#include <hip/hip_runtime.h>
#include <stdint.h>

#define B_ 10000
#define T_ 80
#define E_ 100
#define U_ 64

typedef __attribute__((ext_vector_type(8))) short bf16x8;
typedef __attribute__((ext_vector_type(4))) float f32x4;

union FragU { bf16x8 v; uint32_t u[4]; short s[8]; };

__device__ __forceinline__ void split_bf16(float w, short& hi, short& lo) {
    uint32_t wb  = __float_as_uint(w);
    uint32_t hib = wb & 0xFFFF0000u;
    float rem = w - __uint_as_float(hib);   // exact
    hi = (short)(hib >> 16);
    lo = (short)(__float_as_uint(rem) >> 16);
}

__device__ __forceinline__ float tanh_fast(float v) {
    float e  = __expf(2.0f * fabsf(v));     // overflow -> inf -> tanh -> 1
    float tn = 1.0f - 2.0f / (e + 1.0f);
    return copysignf(tn, v);
}

__device__ __forceinline__ float sigmoid_f(float logit) {
    if (logit >= 0.0f) return 1.0f / (1.0f + __expf(-logit));
    float e = __expf(logit);
    return e / (1.0f + e);
}

// gather emb row slice for this lane: 32 floats at k0 = 8q + 32kk (K padded 100->128)
__device__ __forceinline__ void gather_x(const float* __restrict__ erow, int q, f32x4 xf[8]) {
    #pragma unroll
    for (int kk = 0; kk < 3; ++kk) {            // k0 max = 24+64 = 88, +7 = 95 < 100: always valid
        const int k0 = 8 * q + 32 * kk;
        xf[2 * kk]     = *(const f32x4*)(erow + k0);
        xf[2 * kk + 1] = *(const f32x4*)(erow + k0 + 4);
    }
    // kk = 3: k0 = 96 + 8q; only q==0 has 4 valid floats (96..99)
    f32x4 z = {0.0f, 0.0f, 0.0f, 0.0f};
    xf[6] = (q == 0) ? *(const f32x4*)(erow + 96) : z;
    xf[7] = z;
}

// convert 32 gathered f32 -> 4 bf16 A-fragments (truncation; packs (x[2j+1]<<16)|x[2j])
__device__ __forceinline__ void cvt_x(const f32x4 xf[8], FragU ax[4]) {
    #pragma unroll
    for (int kk = 0; kk < 4; ++kk)
        #pragma unroll
        for (int h = 0; h < 2; ++h) {
            f32x4 v = xf[2 * kk + h];
            ax[kk].u[2 * h]     = __builtin_amdgcn_perm(__float_as_uint(v[1]), __float_as_uint(v[0]), 0x07060302u);
            ax[kk].u[2 * h + 1] = __builtin_amdgcn_perm(__float_as_uint(v[3]), __float_as_uint(v[2]), 0x07060302u);
        }
}

// ============ fully fused: 1 wave = 16 batch rows, 80 steps, no barriers, no workspace ============
__global__ __launch_bounds__(64, 1)
void rnn_fused(const int* __restrict__ tokens, const float* __restrict__ emb,
               const float* __restrict__ Wx, const float* __restrict__ Wh,
               const float* __restrict__ bias, const float* __restrict__ Wfc,
               const float* __restrict__ bfc, float* __restrict__ out)
{
    __shared__ __align__(16) uint32_t H2[16 * 64];  // packed (hi<<16|lo) bf16 of h, XOR-swizzled
    __shared__ int toks[16 * T_];

    const int l = threadIdx.x;
    const int q = l >> 4, p = l & 15;
    const int R0 = blockIdx.x * 16;
    const int swz = (p & 7) << 2;

    // ---- stage tokens (coalesced: [r][t] contiguous) ----
    for (int i = l; i < 16 * T_; i += 64) toks[i] = tokens[R0 * T_ + i];

    // ---- Wx fragments (K padded 100->128), hi/lo 2-term ----
    FragU wxh[4][4], wxl[4][4];
    #pragma unroll
    for (int kk = 0; kk < 4; ++kk)
        #pragma unroll
        for (int n = 0; n < 4; ++n)
            #pragma unroll
            for (int j = 0; j < 8; ++j) {
                int k = 8 * q + j + 32 * kk;
                float w = (k < E_) ? Wx[k * U_ + 16 * n + p] : 0.0f;
                split_bf16(w, wxh[kk][n].s[j], wxl[kk][n].s[j]);
            }

    // ---- Wh fragments, hi/lo ----
    FragU whh[2][4], whl[2][4];
    #pragma unroll
    for (int kk = 0; kk < 2; ++kk)
        #pragma unroll
        for (int n = 0; n < 4; ++n)
            #pragma unroll
            for (int j = 0; j < 8; ++j) {
                float w = Wh[(8 * q + j + 32 * kk) * U_ + 16 * n + p];
                split_bf16(w, whh[kk][n].s[j], whl[kk][n].s[j]);
            }

    float bv[4], wf[4];
    #pragma unroll
    for (int n = 0; n < 4; ++n) { bv[n] = bias[16 * n + p]; wf[n] = Wfc[16 * n + p]; }

    // ---- h(0) = 0 ----
    #pragma unroll
    for (int n = 0; n < 4; ++n)
        #pragma unroll
        for (int r = 0; r < 4; ++r) {
            int row = 4 * q + r;
            H2[row * 64 + ((16 * n + p) ^ ((row & 7) << 2))] = 0u;
        }
    __syncthreads();   // single wave: cheap; makes toks/H2 staging ordering explicit

    // ---- x(0) ----
    FragU ax[4];
    {
        int tok0 = toks[p * T_ + 0];
        f32x4 xf0[8];
        gather_x(emb + (size_t)tok0 * E_, q, xf0);
        cvt_x(xf0, ax);
    }

    const uint32_t* Hrow = H2 + p * 64;
    float hl[16];

    for (int t = 0; t < T_; ++t) {
        // C-init = bias
        f32x4 acc[4];
        #pragma unroll
        for (int n = 0; n < 4; ++n) { f32x4 a = {bv[n], bv[n], bv[n], bv[n]}; acc[n] = a; }

        // prefetch x(t+1) — L2/L3-cached emb gather, hidden under this step's compute
        const int tn = (t + 1 < T_) ? t + 1 : T_ - 1;
        const int tokn = toks[p * T_ + tn];
        f32x4 xf[8];
        gather_x(emb + (size_t)tokn * E_, q, xf);

        // ---- projection: acc += x(t) @ Wx  (x single-bf16, Wx hi/lo: 32 MFMA) ----
        #pragma unroll
        for (int kk = 0; kk < 4; ++kk)
            #pragma unroll
            for (int n = 0; n < 4; ++n) {
                acc[n] = __builtin_amdgcn_mfma_f32_16x16x32_bf16(ax[kk].v, wxh[kk][n].v, acc[n], 0, 0, 0);
                acc[n] = __builtin_amdgcn_mfma_f32_16x16x32_bf16(ax[kk].v, wxl[kk][n].v, acc[n], 0, 0, 0);
            }

        // ---- h(t-1) A-fragments from LDS (swizzled transpose read + hi/lo unpack) ----
        FragU ah[2], al[2];
        #pragma unroll
        for (int kk = 0; kk < 2; ++kk) {
            const int c0 = 8 * q + 32 * kk;
            uint4 wa = *(const uint4*)(Hrow + (c0 ^ swz));
            uint4 wb = *(const uint4*)(Hrow + ((c0 + 4) ^ swz));
            ah[kk].u[0] = __builtin_amdgcn_perm(wa.y, wa.x, 0x07060302u);
            ah[kk].u[1] = __builtin_amdgcn_perm(wa.w, wa.z, 0x07060302u);
            ah[kk].u[2] = __builtin_amdgcn_perm(wb.y, wb.x, 0x07060302u);
            ah[kk].u[3] = __builtin_amdgcn_perm(wb.w, wb.z, 0x07060302u);
            al[kk].u[0] = __builtin_amdgcn_perm(wa.y, wa.x, 0x05040100u);
            al[kk].u[1] = __builtin_amdgcn_perm(wa.w, wa.z, 0x05040100u);
            al[kk].u[2] = __builtin_amdgcn_perm(wb.y, wb.x, 0x05040100u);
            al[kk].u[3] = __builtin_amdgcn_perm(wb.w, wb.z, 0x05040100u);
        }

        // ---- recurrence: acc += h @ Wh  (3-term hi/lo: 24 MFMA) ----
        #pragma unroll
        for (int kk = 0; kk < 2; ++kk)
            #pragma unroll
            for (int n = 0; n < 4; ++n) {
                acc[n] = __builtin_amdgcn_mfma_f32_16x16x32_bf16(ah[kk].v, whh[kk][n].v, acc[n], 0, 0, 0);
                acc[n] = __builtin_amdgcn_mfma_f32_16x16x32_bf16(al[kk].v, whh[kk][n].v, acc[n], 0, 0, 0);
                acc[n] = __builtin_amdgcn_mfma_f32_16x16x32_bf16(ah[kk].v, whl[kk][n].v, acc[n], 0, 0, 0);
            }

        // ---- tanh, pack hi|lo back to LDS ----
        #pragma unroll
        for (int n = 0; n < 4; ++n)
            #pragma unroll
            for (int r = 0; r < 4; ++r) {
                float h = tanh_fast(acc[n][r]);
                hl[r * 4 + n] = h;
                uint32_t hb  = __float_as_uint(h);
                uint32_t hib = hb & 0xFFFF0000u;
                float rem = h - __uint_as_float(hib);
                uint32_t packed = hib | (__float_as_uint(rem) >> 16);
                int row = 4 * q + r;
                H2[row * 64 + ((16 * n + p) ^ ((row & 7) << 2))] = packed;
            }

        // rotate prefetched x into A-fragments for step t+1
        cvt_x(xf, ax);
    }

    // ---- logits + sigmoid ----
    #pragma unroll
    for (int r = 0; r < 4; ++r) {
        float part = hl[r * 4 + 0] * wf[0] + hl[r * 4 + 1] * wf[1]
                   + hl[r * 4 + 2] * wf[2] + hl[r * 4 + 3] * wf[3];
        part += __shfl_xor(part, 1);
        part += __shfl_xor(part, 2);
        part += __shfl_xor(part, 4);
        part += __shfl_xor(part, 8);
        if (p == 0) out[R0 + 4 * q + r] = sigmoid_f(part + bfc[0]);
    }
}

extern "C" void kernel_launch(void* const* d_in, const int* in_sizes, int n_in,
                              void* d_out, int out_size, void* d_ws, size_t ws_size,
                              hipStream_t stream) {
    const int*   tokens = (const int*)  d_in[0];
    const float* emb    = (const float*)d_in[1];
    const float* Wx     = (const float*)d_in[2];
    const float* Wh     = (const float*)d_in[3];
    const float* b      = (const float*)d_in[4];
    const float* Wfc    = (const float*)d_in[5];
    const float* bfc    = (const float*)d_in[6];
    float* out          = (float*)d_out;

    rnn_fused<<<B_ / 16, 64, 0, stream>>>(tokens, emb, Wx, Wh, b, Wfc, bfc, out);
}